// Round 9
// baseline (1629.786 us; speedup 1.0000x reference)
//
#include <hip/hip_runtime.h>
#include <math.h>

// Problem constants (from reference)
#define T_TOK 16384
#define DIM   768
#define HID   3072
#define NE    5
#define MT    65            // max 128-row m-tiles per expert bucket (cap 8320 rows)
#define HCAP  (MT * 128)
#define CSTR  32            // counts stride (ints) -> one 128B line per expert
#define EPSF  2.2204460492503131e-16f

typedef short bf16x8  __attribute__((ext_vector_type(8)));   // 8 bf16 in 4 VGPRs
typedef float f32x4   __attribute__((ext_vector_type(4)));
typedef float f32x16  __attribute__((ext_vector_type(16)));

#define MFMA16(A, B, C) __builtin_amdgcn_mfma_f32_16x16x32_bf16((A), (B), (C), 0, 0, 0)
#define MFMA32(A, B, C) __builtin_amdgcn_mfma_f32_32x32x16_bf16((A), (B), (C), 0, 0, 0)

__device__ __forceinline__ unsigned short f2bf(float f) {
    unsigned int u = __float_as_uint(f);
    unsigned int r = (u + 0x7fffu + ((u >> 16) & 1u)) >> 16;  // RNE
    return (unsigned short)r;
}

__device__ __forceinline__ void gld16(const void* g, void* l) {
    __builtin_amdgcn_global_load_lds(
        (const __attribute__((address_space(1))) void*)g,
        (__attribute__((address_space(3))) void*)l, 16, 0, 0);
}

// bijective XCD-chunk swizzle (m204): each XCD owns a CONTIGUOUS chunk of the
// work index space (mt-major -> A/h tiles stay L2-resident per XCD).
__device__ __forceinline__ int xcd_swz(int orig, int nwg) {
    int q = nwg >> 3, r = nwg & 7;
    int xcd = orig & 7, off = orig >> 3;
    int base = (xcd < r) ? xcd * (q + 1) : r * (q + 1) + (xcd - r) * q;
    return base + off;
}

// ---------------- prep: W1 -> LDS-tile-linear, XOR-swizzled bf16 ----------------
// tile t = (e*24 + nb)*12 + kb ; W1p[t*8192 + n*64 + p*8 + j] =
//   bf16( W1[e][ kb*64 + (p^(n&7))*8 + j ][ nb*128 + n ] )
__global__ void prep_w1p(const float* __restrict__ W1, unsigned short* __restrict__ W1p) {
    int idx = blockIdx.x * 256 + threadIdx.x;
    if (idx >= NE * 24 * 12 * 128 * 8) return;
    int p = idx & 7;
    int n = (idx >> 3) & 127;
    int t = idx >> 10;
    int kb = t % 12; t /= 12;
    int nb = t % 24; int e = t / 24;
    int klog = kb * 64 + (p ^ (n & 7)) * 8;
    const float* src = W1 + ((size_t)e * DIM + klog) * HID + nb * 128 + n;
    bf16x8 v;
    #pragma unroll
    for (int j = 0; j < 8; ++j) v[j] = (short)f2bf(src[(size_t)j * HID]);
    *reinterpret_cast<bf16x8*>(W1p + (size_t)idx * 8) = v;
}

// tile t = (e*6 + nb)*48 + kb
__global__ void prep_w2p(const float* __restrict__ W2, unsigned short* __restrict__ W2p) {
    int idx = blockIdx.x * 256 + threadIdx.x;
    if (idx >= NE * 6 * 48 * 128 * 8) return;
    int p = idx & 7;
    int n = (idx >> 3) & 127;
    int t = idx >> 10;
    int kb = t % 48; t /= 48;
    int nb = t % 6; int e = t / 6;
    int klog = kb * 64 + (p ^ (n & 7)) * 8;
    const float* src = W2 + ((size_t)e * HID + klog) * DIM + nb * 128 + n;
    bf16x8 v;
    #pragma unroll
    for (int j = 0; j < 8; ++j) v[j] = (short)f2bf(src[(size_t)j * DIM]);
    *reinterpret_cast<bf16x8*>(W2p + (size_t)idx * 8) = v;
}

// ---------------- gating + x cast, block-aggregated scatter ----------------
__global__ __launch_bounds__(256) void gate_kernel(
    const float* __restrict__ x, const float* __restrict__ wg,
    unsigned short* __restrict__ xb, int* __restrict__ counts,
    int* __restrict__ btok, float* __restrict__ bgate) {
    __shared__ int   s_e[2][64];
    __shared__ float s_g[2][64];
    __shared__ int   lcnt[NE];
    __shared__ int   gbase[NE];

    const int tid = threadIdx.x;
    if (tid < NE) lcnt[tid] = 0;
    const int grp = tid >> 4, l16 = tid & 15;
    const int t0 = blockIdx.x * 64 + grp * 4;

    double acc[4][NE];
    #pragma unroll
    for (int tt = 0; tt < 4; ++tt)
        #pragma unroll
        for (int e = 0; e < NE; ++e) acc[tt][e] = 0.0;

    for (int i = 0; i < 12; ++i) {
        const int dbase = i * 64 + l16 * 4;
        float4 xv[4];
        #pragma unroll
        for (int tt = 0; tt < 4; ++tt) {
            xv[tt] = *reinterpret_cast<const float4*>(x + (size_t)(t0 + tt) * DIM + dbase);
            ushort4 o;
            o.x = f2bf(xv[tt].x); o.y = f2bf(xv[tt].y);
            o.z = f2bf(xv[tt].z); o.w = f2bf(xv[tt].w);
            *reinterpret_cast<ushort4*>(xb + (size_t)(t0 + tt) * DIM + dbase) = o;
        }
        #pragma unroll
        for (int j = 0; j < 4; ++j) {
            const int d = dbase + j;
            float w0 = wg[d * NE + 0], w1 = wg[d * NE + 1], w2 = wg[d * NE + 2];
            float w3 = wg[d * NE + 3], w4 = wg[d * NE + 4];
            #pragma unroll
            for (int tt = 0; tt < 4; ++tt) {
                double xd = (double)((&xv[tt].x)[j]);
                acc[tt][0] += xd * (double)w0;
                acc[tt][1] += xd * (double)w1;
                acc[tt][2] += xd * (double)w2;
                acc[tt][3] += xd * (double)w3;
                acc[tt][4] += xd * (double)w4;
            }
        }
    }
    #pragma unroll
    for (int off = 8; off; off >>= 1)
        #pragma unroll
        for (int tt = 0; tt < 4; ++tt)
            #pragma unroll
            for (int e = 0; e < NE; ++e)
                acc[tt][e] += __shfl_down(acc[tt][e], off, 16);

    if (l16 == 0) {
        #pragma unroll
        for (int tt = 0; tt < 4; ++tt) {
            double v[NE] = {acc[tt][0], acc[tt][1], acc[tt][2], acc[tt][3], acc[tt][4]};
            int i0 = 0;
            for (int e = 1; e < NE; ++e) if (v[e] > v[i0]) i0 = e;
            int i1 = -1;
            for (int e = 0; e < NE; ++e) {
                if (e == i0) continue;
                if (i1 < 0 || v[e] > v[i1]) i1 = e;
            }
            float e1 = expf((float)(v[i1] - v[i0]));
            float g0 = 1.0f / (1.0f + e1);
            int li = grp * 4 + tt;
            s_e[0][li] = i0;  s_g[0][li] = g0;
            s_e[1][li] = i1;  s_g[1][li] = e1 * g0;
        }
    }
    __syncthreads();

    int mye = 0, myoff = 0, mytok = 0;
    float myg = 0.0f;
    if (tid < 128) {
        int li = tid >> 1, which = tid & 1;
        mye = s_e[which][li];
        myg = s_g[which][li];
        mytok = blockIdx.x * 64 + li;
        myoff = atomicAdd(&lcnt[mye], 1);
    }
    __syncthreads();
    if (tid < NE) gbase[tid] = atomicAdd(&counts[tid * CSTR], lcnt[tid]);
    __syncthreads();
    if (tid < 128) {
        int p = gbase[mye] + myoff;
        btok[mye * T_TOK + p] = mytok;
        bgate[mye * T_TOK + p] = myg;
    }
}

// ---------------- combo GEMM kernel (m97-style 128x128 tile, BK=64) ----------------
// Round-9: r8 kernel + CORRECTNESS FIX. With top-2 routing, a token lives in two
// expert buckets; if both G2 experts are co-scheduled in one launch, two blocks
// RMW the same out[token] -> lost updates (r8's absmax=4 failure). Fix: launches
// with g2n>1 use atomicAdd (still coalesced, LDS-transposed layout); single-G2
// launches keep the faster non-atomic float4 RMW. Branch is launch-uniform.
// Compile contract = verified r5: launch_bounds(256,4), 60 VGPR, 33.8 KB LDS.
__global__ __launch_bounds__(256, 4) void combo_kernel(
    const unsigned short* __restrict__ xb,
    const unsigned short* __restrict__ W1p,
    const unsigned short* __restrict__ W2p,
    const float* __restrict__ b1, const float* __restrict__ b2,
    const int* __restrict__ counts, const int* __restrict__ btok,
    const float* __restrict__ bgate,
    unsigned short* __restrict__ hall, int nslots,
    float* __restrict__ out, int g1s, int g1n, int g2s, int g2n, int g2atomic) {
    __shared__ __align__(16) unsigned short smem[2 * 128 * 64];   // 32 KB
    __shared__ int   sst[128];
    __shared__ float ssg[128];
    unsigned short* As = smem;
    unsigned short* Bs = smem + 128 * 64;

    const int g2seg = MT * 6, g1seg = MT * 24;
    int bx = blockIdx.x;
    const int g2tot = g2n * g2seg;
    const bool isG2 = bx < g2tot;
    int e, mt, nt;
    if (isG2) {
        e = g2s + bx / g2seg;
        int w = xcd_swz(bx % g2seg, g2seg);
        mt = w / 6;  nt = w % 6;
    } else {
        bx -= g2tot;
        e = g1s + bx / g1seg;
        int w = xcd_swz(bx % g1seg, g1seg);
        mt = w / 24; nt = w % 24;
    }
    const int cnt = counts[e * CSTR];
    const int m0 = mt * 128;
    if (m0 >= cnt) return;
    unsigned short* hbuf = hall + (size_t)(e % nslots) * ((size_t)HCAP * HID);

    const int tid = threadIdx.x;
    const int wv = tid >> 6, lane = tid & 63;
    const int wm = wv >> 1, wn = wv & 1;
    const int col = lane & 15, quad = lane >> 4;
    const int l8 = lane & 7, r8 = lane >> 3;

    const unsigned short* aptr[4];
    if (isG2) {
        if (tid < 128) {
            int pos = m0 + tid;
            sst[tid] = (pos < cnt) ? btok[e * T_TOK + pos] : 0;
            ssg[tid] = (pos < cnt) ? bgate[e * T_TOK + pos] : 0.0f;
        }
        #pragma unroll
        for (int q = 0; q < 4; ++q) {
            int r = wv * 32 + q * 8 + r8;
            aptr[q] = hbuf + (size_t)(m0 + r) * HID + (l8 ^ r8) * 8;
        }
    } else {
        #pragma unroll
        for (int q = 0; q < 4; ++q) {
            int r = wv * 32 + q * 8 + r8;
            int pos = m0 + r;
            int tok = btok[e * T_TOK + (pos < cnt ? pos : 0)];
            aptr[q] = xb + (size_t)tok * DIM + (l8 ^ r8) * 8;
        }
    }
    const unsigned short* btile = isG2
        ? W2p + ((size_t)(e * 6 + nt)) * 48 * 8192
        : W1p + ((size_t)(e * 24 + nt)) * 12 * 8192;
    const int ksteps = isG2 ? 48 : 12;

    f32x4 acc[4][4];
    #pragma unroll
    for (int i = 0; i < 4; ++i)
        #pragma unroll
        for (int j = 0; j < 4; ++j)
            acc[i][j] = (f32x4){0.f, 0.f, 0.f, 0.f};

    for (int ks = 0; ks < ksteps; ++ks) {
        const unsigned short* bk = btile + (size_t)ks * 8192 + (size_t)wv * 2048 + lane * 8;
        #pragma unroll
        for (int q = 0; q < 4; ++q)
            gld16(aptr[q] + ks * 64, &As[(wv * 4 + q) * 512]);
        #pragma unroll
        for (int q = 0; q < 4; ++q)
            gld16(bk + q * 512, &Bs[(wv * 4 + q) * 512]);
        __syncthreads();
        #pragma unroll
        for (int kf = 0; kf < 2; ++kf) {
            const int p = ((kf * 4 + quad) ^ l8) * 8;
            bf16x8 a[4], b[4];
            #pragma unroll
            for (int i = 0; i < 4; ++i)
                a[i] = *reinterpret_cast<const bf16x8*>(&As[(wm * 64 + i * 16 + col) * 64 + p]);
            #pragma unroll
            for (int i = 0; i < 4; ++i)
                b[i] = *reinterpret_cast<const bf16x8*>(&Bs[(wn * 64 + i * 16 + col) * 64 + p]);
            #pragma unroll
            for (int i = 0; i < 4; ++i)
                #pragma unroll
                for (int j = 0; j < 4; ++j)
                    acc[i][j] = MFMA16(a[i], b[j], acc[i][j]);
        }
        __syncthreads();
    }
    // final in-loop __syncthreads fences all LDS reads; smem is free as scratch.

    const int nb0 = nt * 128 + wn * 64;
    if (!isG2) {
        // ---- coalesced h epilogue: padded LDS transpose (stride 132), 16B stores ----
        unsigned short (*X)[132] = reinterpret_cast<unsigned short (*)[132]>(smem);
        #pragma unroll
        for (int i = 0; i < 4; ++i) {
            #pragma unroll
            for (int j = 0; j < 4; ++j) {
                float bias = b1[e * HID + nb0 + j * 16 + col];
                #pragma unroll
                for (int r = 0; r < 4; ++r) {
                    float v = acc[i][j][r] + bias;
                    float gl = 0.5f * v * (1.0f + erff(v * 0.70710678118654752f));
                    X[wm * 16 + quad * 4 + r][wn * 64 + j * 16 + col] = f2bf(gl);
                }
            }
            __syncthreads();
            {
                int lr = tid >> 3, g = tid & 7;
                int grow = m0 + (lr >> 4) * 64 + i * 16 + (lr & 15);
                unsigned short* dst = hbuf + (size_t)grow * HID + nt * 128;
                *reinterpret_cast<bf16x8*>(dst + g * 8) =
                    *reinterpret_cast<const bf16x8*>(&X[lr][g * 8]);
                *reinterpret_cast<bf16x8*>(dst + 64 + g * 8) =
                    *reinterpret_cast<const bf16x8*>(&X[lr][64 + g * 8]);
            }
            __syncthreads();
        }
    } else {
        // ---- coalesced out epilogue: padded f32 transpose ----
        // g2atomic==0: exclusive (token,col) ownership within the launch -> float4 RMW.
        // g2atomic==1: multiple G2 experts co-scheduled (token can be in two buckets)
        //              -> per-float atomicAdd, still fully coalesced.
        float (*Xf)[132] = reinterpret_cast<float (*)[132]>(smem);  // 16.9 KB of 32 KB
        #pragma unroll
        for (int i = 0; i < 4; ++i) {
            #pragma unroll
            for (int j = 0; j < 4; ++j) {
                float bias = b2[e * DIM + nb0 + j * 16 + col];
                #pragma unroll
                for (int r = 0; r < 4; ++r) {
                    int lrow = wm * 64 + i * 16 + quad * 4 + r;
                    float g = ssg[lrow];
                    float v = acc[i][j][r] + bias;
                    Xf[wm * 16 + quad * 4 + r][wn * 64 + j * 16 + col] =
                        (g > 0.0f) ? g * expf(v) : 0.0f;
                }
            }
            __syncthreads();
            {
                int lr = tid >> 3, gq = tid & 7;
                int lrow = (lr >> 4) * 64 + i * 16 + (lr & 15);
                if (m0 + lrow < cnt) {   // guard: padded rows must not write (token-0 race)
                    float* dst = out + (size_t)sst[lrow] * DIM + nt * 128 + gq * 16;
                    const float* src = &Xf[lr][gq * 16];
                    if (g2atomic) {
                        #pragma unroll
                        for (int q = 0; q < 16; ++q)
                            atomicAdd(dst + q, src[q]);
                    } else {
                        #pragma unroll
                        for (int q = 0; q < 4; ++q) {
                            float4 o = *reinterpret_cast<float4*>(dst + q * 4);
                            float4 a = *reinterpret_cast<const float4*>(src + q * 4);
                            o.x += a.x; o.y += a.y; o.z += a.z; o.w += a.w;
                            *reinterpret_cast<float4*>(dst + q * 4) = o;
                        }
                    }
                }
            }
            __syncthreads();
        }
    }
}

// ---------------- final: out = log(acc), eps guard ----------------
__global__ void log_kernel(float* __restrict__ out, int n) {
    int i = blockIdx.x * 256 + threadIdx.x;
    if (i < n) {
        float v = out[i];
        out[i] = logf(v == 0.0f ? EPSF : v);
    }
}

// ================= fallback path (used only if ws too small) =================
__global__ void prep_w1_v2(const float* __restrict__ W1, unsigned short* __restrict__ W1s) {
    int g = blockIdx.x * 4 + (threadIdx.x >> 6);
    int lane = threadIdx.x & 63;
    int kf = g % 48;
    int rest = g / 48;
    int nt2 = rest % 96;
    int e = rest / 96;
    int n = nt2 * 32 + (lane & 31);
    int k0 = kf * 16 + (lane >> 5) * 8;
    const float* src = W1 + ((size_t)e * DIM + k0) * HID + n;
    bf16x8 v;
    #pragma unroll
    for (int j = 0; j < 8; ++j) v[j] = (short)f2bf(src[(size_t)j * HID]);
    *reinterpret_cast<bf16x8*>(W1s + ((size_t)g * 64 + lane) * 8) = v;
}

__global__ void prep_w2_v2(const float* __restrict__ W2, unsigned short* __restrict__ W2s) {
    int g = blockIdx.x * 4 + (threadIdx.x >> 6);
    int lane = threadIdx.x & 63;
    int kf = g % 192;
    int rest = g / 192;
    int nt2 = rest % 24;
    int e = rest / 24;
    int n = nt2 * 32 + (lane & 31);
    int k0 = kf * 16 + (lane >> 5) * 8;
    const float* src = W2 + ((size_t)e * HID + k0) * DIM + n;
    bf16x8 v;
    #pragma unroll
    for (int j = 0; j < 8; ++j) v[j] = (short)f2bf(src[(size_t)j * DIM]);
    *reinterpret_cast<bf16x8*>(W2s + ((size_t)g * 64 + lane) * 8) = v;
}

__global__ __launch_bounds__(512, 2) void expert_v2(
    const unsigned short* __restrict__ xb, const unsigned short* __restrict__ W1s,
    const unsigned short* __restrict__ W2s, const float* __restrict__ b1,
    const float* __restrict__ b2, const int* __restrict__ counts,
    const int* __restrict__ btok, const float* __restrict__ bgate,
    float* __restrict__ out) {
    __shared__ __align__(16) unsigned short xs[64][776];
    __shared__ __align__(16) unsigned short hs[2][64][136];
    __shared__ int   st[64];
    __shared__ float sg[64];

    const int e = blockIdx.y;
    const int cnt = counts[e * CSTR];
    const int m0 = blockIdx.x * 64;
    if (m0 >= cnt) return;

    const int tid = threadIdx.x;
    const int wv = tid >> 6, lane = tid & 63;
    const int l31 = lane & 31, lhi = lane >> 5;

    if (tid < 64) {
        int pos = m0 + tid;
        st[tid] = (pos < cnt) ? btok[e * T_TOK + pos] : 0;
        sg[tid] = (pos < cnt) ? bgate[e * T_TOK + pos] : 0.0f;
    }
    __syncthreads();
    {
        int r = tid >> 3, seg = tid & 7;
        const unsigned short* src = xb + (size_t)st[r] * DIM + seg * 96;
        unsigned short* dst = &xs[r][seg * 96];
        #pragma unroll
        for (int i = 0; i < 12; ++i)
            reinterpret_cast<bf16x8*>(dst)[i] = reinterpret_cast<const bf16x8*>(src)[i];
    }
    __syncthreads();

    const int mt2 = wv & 1, nt2l = wv >> 1;
    f32x16 acc[2][3];
    #pragma unroll
    for (int a_ = 0; a_ < 2; ++a_)
        #pragma unroll
        for (int b_ = 0; b_ < 3; ++b_)
            #pragma unroll
            for (int q = 0; q < 16; ++q) acc[a_][b_][q] = 0.0f;

    const unsigned short* arow = &xs[mt2 * 32 + l31][lhi * 8];
    for (int jc = 0; jc < 24; ++jc) {
        f32x16 c0, c1;
        #pragma unroll
        for (int q = 0; q < 16; ++q) { c0[q] = 0.0f; c1[q] = 0.0f; }
        const unsigned short* bpa =
            W1s + ((size_t)((e * 96 + jc * 4 + nt2l) * 48)) * 512 + lane * 8;
        #pragma unroll
        for (int kf = 0; kf < 48; kf += 2) {
            bf16x8 a0 = *reinterpret_cast<const bf16x8*>(arow + kf * 16);
            bf16x8 b0 = *reinterpret_cast<const bf16x8*>(bpa + (size_t)kf * 512);
            c0 = MFMA32(a0, b0, c0);
            bf16x8 a1 = *reinterpret_cast<const bf16x8*>(arow + kf * 16 + 16);
            bf16x8 b1 = *reinterpret_cast<const bf16x8*>(bpa + (size_t)kf * 512 + 512);
            c1 = MFMA32(a1, b1, c1);
        }
        #pragma unroll
        for (int q = 0; q < 16; ++q) c0[q] += c1[q];
        {
            int colc = nt2l * 32 + l31;
            float bias = b1[e * HID + jc * 128 + colc];
            #pragma unroll
            for (int reg = 0; reg < 16; ++reg) {
                int row = (reg & 3) + 8 * (reg >> 2) + 4 * lhi;
                float v = c0[reg] + bias;
                float gl = 0.5f * v * (1.0f + erff(v * 0.70710678118654752f));
                hs[jc & 1][mt2 * 32 + row][colc] = f2bf(gl);
            }
        }
        __syncthreads();
        const unsigned short* bpb =
            W2s + ((size_t)((e * 24 + wv * 3) * 192 + jc * 8)) * 512 + lane * 8;
        #pragma unroll
        for (int kf = 0; kf < 8; ++kf) {
            bf16x8 af0 = *reinterpret_cast<const bf16x8*>(&hs[jc & 1][l31][kf * 16 + lhi * 8]);
            bf16x8 af1 = *reinterpret_cast<const bf16x8*>(&hs[jc & 1][32 + l31][kf * 16 + lhi * 8]);
            #pragma unroll
            for (int i = 0; i < 3; ++i) {
                bf16x8 bv = *reinterpret_cast<const bf16x8*>(bpb + ((size_t)i * 192 + kf) * 512);
                acc[0][i] = MFMA32(af0, bv, acc[0][i]);
                acc[1][i] = MFMA32(af1, bv, acc[1][i]);
            }
        }
    }
    #pragma unroll
    for (int mt = 0; mt < 2; ++mt) {
        #pragma unroll
        for (int i = 0; i < 3; ++i) {
            int cg = (wv * 3 + i) * 32 + l31;
            float bias2 = b2[e * DIM + cg];
            #pragma unroll
            for (int reg = 0; reg < 16; ++reg) {
                int row = mt * 32 + (reg & 3) + 8 * (reg >> 2) + 4 * lhi;
                float g = sg[row];
                if (g > 0.0f) {
                    float v = acc[mt][i][reg] + bias2;
                    atomicAdd(out + (size_t)st[row] * DIM + cg, g * expf(v));
                }
            }
        }
    }
}

// =====================================================================

extern "C" void kernel_launch(void* const* d_in, const int* in_sizes, int n_in,
                              void* d_out, int out_size, void* d_ws, size_t ws_size,
                              hipStream_t stream) {
    const float* x  = (const float*)d_in[0];
    const float* wg = (const float*)d_in[1];
    const float* W1 = (const float*)d_in[2];
    const float* b1 = (const float*)d_in[3];
    const float* W2 = (const float*)d_in[4];
    const float* b2 = (const float*)d_in[5];
    float* out = (float*)d_out;

    // workspace layout
    char* ws = (char*)d_ws;
    int*            counts = (int*)ws;                                   // 5*128B padded
    int*            btok   = (int*)(ws + 1024);                          // 320 KB
    float*          bgate  = (float*)(ws + 1024 + 327680);               // 320 KB
    unsigned short* xb     = (unsigned short*)(ws + 1024 + 2 * 327680);  // 24 MB
    unsigned short* W1b    = xb + (size_t)T_TOK * DIM;                   // 22.5 MB
    unsigned short* W2b    = W1b + (size_t)NE * DIM * HID;               // 22.5 MB
    unsigned short* hall   = W2b + (size_t)NE * HID * DIM;               // k x 48.75 MB

    const size_t HBsh  = (size_t)HCAP * HID;  // h bucket size in shorts
    const size_t fixed = 1024 + 2 * 327680
        + (size_t)T_TOK * DIM * 2 + 2 * (size_t)NE * DIM * HID * 2;
    auto need = [&](int k) { return fixed + (size_t)k * HBsh * 2; };

    const int g1seg = MT * 24, g2seg = MT * 6;

    hipMemsetAsync(counts, 0, 1024, stream);
    hipMemsetAsync(out, 0, (size_t)out_size * sizeof(float), stream);

    gate_kernel<<<T_TOK / 64, 256, 0, stream>>>(x, wg, xb, counts, btok, bgate);

    if (ws_size >= need(2)) {
        prep_w1p<<<(NE * 24 * 12 * 128 * 8 + 255) / 256, 256, 0, stream>>>(W1, W1b);
        prep_w2p<<<(NE * 6 * 48 * 128 * 8 + 255) / 256, 256, 0, stream>>>(W2, W2b);

        auto launch_combo = [&](int g1s, int g1n, int g2s, int g2n, int nslots) {
            int nb = g1n * g1seg + g2n * g2seg;
            if (nb <= 0) return;
            int g2atomic = (g2n > 1) ? 1 : 0;   // multi-G2 launch -> atomics (top-2 overlap)
            combo_kernel<<<nb, 256, 0, stream>>>(xb, W1b, W2b, b1, b2, counts,
                                                 btok, bgate, hall, nslots, out,
                                                 g1s, g1n, g2s, g2n, g2atomic);
        };

        if (ws_size >= need(5)) {
            // 2-launch: all G1, then all G2 (atomic).
            launch_combo(0, 5, 0, 0, 5);
            launch_combo(0, 0, 0, 5, 5);
        } else if (ws_size >= need(4)) {
            // 4 buckets (slot = e%4; e4 reuses e0's dead slot).
            launch_combo(0, 2, 0, 0, 4);
            launch_combo(2, 2, 0, 1, 4);
            launch_combo(4, 1, 1, 2, 4);
            launch_combo(0, 0, 3, 2, 4);
        } else if (ws_size >= need(3)) {
            // 3 buckets (slot = e%3), 4-launch pipeline, h-slot conflict-free:
            //  L1: G1(0)->s0, G1(1)->s1
            //  L2: G1(2)->s2 | G2(0)<-s0, G2(1)<-s1   [atomic: experts share tokens]
            //  L3: G1(3)->s0, G1(4)->s1 | G2(2)<-s2   [non-atomic]
            //  L4: G2(3)<-s0, G2(4)<-s1               [atomic]
            launch_combo(0, 2, 0, 0, 3);
            launch_combo(2, 1, 0, 2, 3);
            launch_combo(3, 2, 2, 1, 3);
            launch_combo(0, 0, 3, 2, 3);
        } else {
            // 6-launch pipeline: G1(s) + G2(s-1), parity buckets (single-G2 -> RMW).
            for (int s = 0; s < 6; ++s)
                launch_combo(s, (s <= 4) ? 1 : 0, s - 1, (s >= 1) ? 1 : 0, 2);
        }
    } else {
        prep_w1_v2<<<NE * 96 * 48 / 4, 256, 0, stream>>>(W1, W1b);
        prep_w2_v2<<<NE * 24 * 192 / 4, 256, 0, stream>>>(W2, W2b);
        expert_v2<<<dim3(T_TOK / 64, NE), 512, 0, stream>>>(
            xb, W1b, W2b, b1, b2, counts, btok, bgate, out);
    }

    log_kernel<<<(out_size + 255) / 256, 256, 0, stream>>>(out, out_size);
}

// Round 10
// 647.504 us; speedup vs baseline: 2.5170x; 2.5170x over previous
//
#include <hip/hip_runtime.h>
#include <math.h>

// Problem constants (from reference)
#define T_TOK 16384
#define DIM   768
#define HID   3072
#define NE    5
#define MT    65            // max 128-row m-tiles per expert bucket (cap 8320 rows)
#define HCAP  (MT * 128)
#define CSTR  32            // counts stride (ints) -> one 128B line per expert
#define EPSF  2.2204460492503131e-16f

typedef short bf16x8  __attribute__((ext_vector_type(8)));   // 8 bf16 in 4 VGPRs
typedef float f32x4   __attribute__((ext_vector_type(4)));
typedef float f32x16  __attribute__((ext_vector_type(16)));

#define MFMA16(A, B, C) __builtin_amdgcn_mfma_f32_16x16x32_bf16((A), (B), (C), 0, 0, 0)
#define MFMA32(A, B, C) __builtin_amdgcn_mfma_f32_32x32x16_bf16((A), (B), (C), 0, 0, 0)

__device__ __forceinline__ unsigned short f2bf(float f) {
    unsigned int u = __float_as_uint(f);
    unsigned int r = (u + 0x7fffu + ((u >> 16) & 1u)) >> 16;  // RNE
    return (unsigned short)r;
}

__device__ __forceinline__ void gld16(const void* g, void* l) {
    __builtin_amdgcn_global_load_lds(
        (const __attribute__((address_space(1))) void*)g,
        (__attribute__((address_space(3))) void*)l, 16, 0, 0);
}

// bijective XCD-chunk swizzle (m204): each XCD owns a CONTIGUOUS chunk of the
// work index space (mt-major -> A/h tiles stay L2-resident per XCD).
__device__ __forceinline__ int xcd_swz(int orig, int nwg) {
    int q = nwg >> 3, r = nwg & 7;
    int xcd = orig & 7, off = orig >> 3;
    int base = (xcd < r) ? xcd * (q + 1) : r * (q + 1) + (xcd - r) * q;
    return base + off;
}

// ---------------- prep: W1 -> LDS-tile-linear, XOR-swizzled bf16 ----------------
// tile t = (e*24 + nb)*12 + kb ; W1p[t*8192 + n*64 + p*8 + j] =
//   bf16( W1[e][ kb*64 + (p^(n&7))*8 + j ][ nb*128 + n ] )
__global__ void prep_w1p(const float* __restrict__ W1, unsigned short* __restrict__ W1p) {
    int idx = blockIdx.x * 256 + threadIdx.x;
    if (idx >= NE * 24 * 12 * 128 * 8) return;
    int p = idx & 7;
    int n = (idx >> 3) & 127;
    int t = idx >> 10;
    int kb = t % 12; t /= 12;
    int nb = t % 24; int e = t / 24;
    int klog = kb * 64 + (p ^ (n & 7)) * 8;
    const float* src = W1 + ((size_t)e * DIM + klog) * HID + nb * 128 + n;
    bf16x8 v;
    #pragma unroll
    for (int j = 0; j < 8; ++j) v[j] = (short)f2bf(src[(size_t)j * HID]);
    *reinterpret_cast<bf16x8*>(W1p + (size_t)idx * 8) = v;
}

// tile t = (e*6 + nb)*48 + kb
__global__ void prep_w2p(const float* __restrict__ W2, unsigned short* __restrict__ W2p) {
    int idx = blockIdx.x * 256 + threadIdx.x;
    if (idx >= NE * 6 * 48 * 128 * 8) return;
    int p = idx & 7;
    int n = (idx >> 3) & 127;
    int t = idx >> 10;
    int kb = t % 48; t /= 48;
    int nb = t % 6; int e = t / 6;
    int klog = kb * 64 + (p ^ (n & 7)) * 8;
    const float* src = W2 + ((size_t)e * HID + klog) * DIM + nb * 128 + n;
    bf16x8 v;
    #pragma unroll
    for (int j = 0; j < 8; ++j) v[j] = (short)f2bf(src[(size_t)j * DIM]);
    *reinterpret_cast<bf16x8*>(W2p + (size_t)idx * 8) = v;
}

// ---------------- gating + x cast, block-aggregated scatter ----------------
__global__ __launch_bounds__(256) void gate_kernel(
    const float* __restrict__ x, const float* __restrict__ wg,
    unsigned short* __restrict__ xb, int* __restrict__ counts,
    int* __restrict__ btok, float* __restrict__ bgate) {
    __shared__ int   s_e[2][64];
    __shared__ float s_g[2][64];
    __shared__ int   lcnt[NE];
    __shared__ int   gbase[NE];

    const int tid = threadIdx.x;
    if (tid < NE) lcnt[tid] = 0;
    const int grp = tid >> 4, l16 = tid & 15;
    const int t0 = blockIdx.x * 64 + grp * 4;

    double acc[4][NE];
    #pragma unroll
    for (int tt = 0; tt < 4; ++tt)
        #pragma unroll
        for (int e = 0; e < NE; ++e) acc[tt][e] = 0.0;

    for (int i = 0; i < 12; ++i) {
        const int dbase = i * 64 + l16 * 4;
        float4 xv[4];
        #pragma unroll
        for (int tt = 0; tt < 4; ++tt) {
            xv[tt] = *reinterpret_cast<const float4*>(x + (size_t)(t0 + tt) * DIM + dbase);
            ushort4 o;
            o.x = f2bf(xv[tt].x); o.y = f2bf(xv[tt].y);
            o.z = f2bf(xv[tt].z); o.w = f2bf(xv[tt].w);
            *reinterpret_cast<ushort4*>(xb + (size_t)(t0 + tt) * DIM + dbase) = o;
        }
        #pragma unroll
        for (int j = 0; j < 4; ++j) {
            const int d = dbase + j;
            float w0 = wg[d * NE + 0], w1 = wg[d * NE + 1], w2 = wg[d * NE + 2];
            float w3 = wg[d * NE + 3], w4 = wg[d * NE + 4];
            #pragma unroll
            for (int tt = 0; tt < 4; ++tt) {
                double xd = (double)((&xv[tt].x)[j]);
                acc[tt][0] += xd * (double)w0;
                acc[tt][1] += xd * (double)w1;
                acc[tt][2] += xd * (double)w2;
                acc[tt][3] += xd * (double)w3;
                acc[tt][4] += xd * (double)w4;
            }
        }
    }
    #pragma unroll
    for (int off = 8; off; off >>= 1)
        #pragma unroll
        for (int tt = 0; tt < 4; ++tt)
            #pragma unroll
            for (int e = 0; e < NE; ++e)
                acc[tt][e] += __shfl_down(acc[tt][e], off, 16);

    if (l16 == 0) {
        #pragma unroll
        for (int tt = 0; tt < 4; ++tt) {
            double v[NE] = {acc[tt][0], acc[tt][1], acc[tt][2], acc[tt][3], acc[tt][4]};
            int i0 = 0;
            for (int e = 1; e < NE; ++e) if (v[e] > v[i0]) i0 = e;
            int i1 = -1;
            for (int e = 0; e < NE; ++e) {
                if (e == i0) continue;
                if (i1 < 0 || v[e] > v[i1]) i1 = e;
            }
            float e1 = expf((float)(v[i1] - v[i0]));
            float g0 = 1.0f / (1.0f + e1);
            int li = grp * 4 + tt;
            s_e[0][li] = i0;  s_g[0][li] = g0;
            s_e[1][li] = i1;  s_g[1][li] = e1 * g0;
        }
    }
    __syncthreads();

    int mye = 0, myoff = 0, mytok = 0;
    float myg = 0.0f;
    if (tid < 128) {
        int li = tid >> 1, which = tid & 1;
        mye = s_e[which][li];
        myg = s_g[which][li];
        mytok = blockIdx.x * 64 + li;
        myoff = atomicAdd(&lcnt[mye], 1);
    }
    __syncthreads();
    if (tid < NE) gbase[tid] = atomicAdd(&counts[tid * CSTR], lcnt[tid]);
    __syncthreads();
    if (tid < 128) {
        int p = gbase[mye] + myoff;
        btok[mye * T_TOK + p] = mytok;
        bgate[mye * T_TOK + p] = myg;
    }
}

// ---------------- combo GEMM kernel (m97-style 128x128 tile, BK=64) ----------------
// Round-10: r9 kernel with the atomic drain's ADDRESS PATTERN fixed. r9 had each
// thread own 16 CONSECUTIVE floats (64B) -> a wave's lanes were 64B apart per
// atomicAdd -> 64 sectors/instr, 6x write amplification (354MB, 640us launches).
// Fix: flat-order drain (flat = tid + k*256 -> row=flat>>7, col=flat&127) so the
// wave's 64 lanes hit 64 CONSECUTIVE floats (256B = 4 sectors/instr); same
// 64 atomics/thread as the r0-proven epilogue. Non-atomic path unchanged.
__global__ __launch_bounds__(256, 4) void combo_kernel(
    const unsigned short* __restrict__ xb,
    const unsigned short* __restrict__ W1p,
    const unsigned short* __restrict__ W2p,
    const float* __restrict__ b1, const float* __restrict__ b2,
    const int* __restrict__ counts, const int* __restrict__ btok,
    const float* __restrict__ bgate,
    unsigned short* __restrict__ hall, int nslots,
    float* __restrict__ out, int g1s, int g1n, int g2s, int g2n, int g2atomic) {
    __shared__ __align__(16) unsigned short smem[2 * 128 * 64];   // 32 KB
    __shared__ int   sst[128];
    __shared__ float ssg[128];
    unsigned short* As = smem;
    unsigned short* Bs = smem + 128 * 64;

    const int g2seg = MT * 6, g1seg = MT * 24;
    int bx = blockIdx.x;
    const int g2tot = g2n * g2seg;
    const bool isG2 = bx < g2tot;
    int e, mt, nt;
    if (isG2) {
        e = g2s + bx / g2seg;
        int w = xcd_swz(bx % g2seg, g2seg);
        mt = w / 6;  nt = w % 6;
    } else {
        bx -= g2tot;
        e = g1s + bx / g1seg;
        int w = xcd_swz(bx % g1seg, g1seg);
        mt = w / 24; nt = w % 24;
    }
    const int cnt = counts[e * CSTR];
    const int m0 = mt * 128;
    if (m0 >= cnt) return;
    unsigned short* hbuf = hall + (size_t)(e % nslots) * ((size_t)HCAP * HID);

    const int tid = threadIdx.x;
    const int wv = tid >> 6, lane = tid & 63;
    const int wm = wv >> 1, wn = wv & 1;
    const int col = lane & 15, quad = lane >> 4;
    const int l8 = lane & 7, r8 = lane >> 3;

    const unsigned short* aptr[4];
    if (isG2) {
        if (tid < 128) {
            int pos = m0 + tid;
            sst[tid] = (pos < cnt) ? btok[e * T_TOK + pos] : 0;
            ssg[tid] = (pos < cnt) ? bgate[e * T_TOK + pos] : 0.0f;
        }
        #pragma unroll
        for (int q = 0; q < 4; ++q) {
            int r = wv * 32 + q * 8 + r8;
            aptr[q] = hbuf + (size_t)(m0 + r) * HID + (l8 ^ r8) * 8;
        }
    } else {
        #pragma unroll
        for (int q = 0; q < 4; ++q) {
            int r = wv * 32 + q * 8 + r8;
            int pos = m0 + r;
            int tok = btok[e * T_TOK + (pos < cnt ? pos : 0)];
            aptr[q] = xb + (size_t)tok * DIM + (l8 ^ r8) * 8;
        }
    }
    const unsigned short* btile = isG2
        ? W2p + ((size_t)(e * 6 + nt)) * 48 * 8192
        : W1p + ((size_t)(e * 24 + nt)) * 12 * 8192;
    const int ksteps = isG2 ? 48 : 12;

    f32x4 acc[4][4];
    #pragma unroll
    for (int i = 0; i < 4; ++i)
        #pragma unroll
        for (int j = 0; j < 4; ++j)
            acc[i][j] = (f32x4){0.f, 0.f, 0.f, 0.f};

    for (int ks = 0; ks < ksteps; ++ks) {
        const unsigned short* bk = btile + (size_t)ks * 8192 + (size_t)wv * 2048 + lane * 8;
        #pragma unroll
        for (int q = 0; q < 4; ++q)
            gld16(aptr[q] + ks * 64, &As[(wv * 4 + q) * 512]);
        #pragma unroll
        for (int q = 0; q < 4; ++q)
            gld16(bk + q * 512, &Bs[(wv * 4 + q) * 512]);
        __syncthreads();
        #pragma unroll
        for (int kf = 0; kf < 2; ++kf) {
            const int p = ((kf * 4 + quad) ^ l8) * 8;
            bf16x8 a[4], b[4];
            #pragma unroll
            for (int i = 0; i < 4; ++i)
                a[i] = *reinterpret_cast<const bf16x8*>(&As[(wm * 64 + i * 16 + col) * 64 + p]);
            #pragma unroll
            for (int i = 0; i < 4; ++i)
                b[i] = *reinterpret_cast<const bf16x8*>(&Bs[(wn * 64 + i * 16 + col) * 64 + p]);
            #pragma unroll
            for (int i = 0; i < 4; ++i)
                #pragma unroll
                for (int j = 0; j < 4; ++j)
                    acc[i][j] = MFMA16(a[i], b[j], acc[i][j]);
        }
        __syncthreads();
    }
    // final in-loop __syncthreads fences all LDS reads; smem is free as scratch.

    const int nb0 = nt * 128 + wn * 64;
    if (!isG2) {
        // ---- coalesced h epilogue: padded LDS transpose (stride 132), 16B stores ----
        unsigned short (*X)[132] = reinterpret_cast<unsigned short (*)[132]>(smem);
        #pragma unroll
        for (int i = 0; i < 4; ++i) {
            #pragma unroll
            for (int j = 0; j < 4; ++j) {
                float bias = b1[e * HID + nb0 + j * 16 + col];
                #pragma unroll
                for (int r = 0; r < 4; ++r) {
                    float v = acc[i][j][r] + bias;
                    float gl = 0.5f * v * (1.0f + erff(v * 0.70710678118654752f));
                    X[wm * 16 + quad * 4 + r][wn * 64 + j * 16 + col] = f2bf(gl);
                }
            }
            __syncthreads();
            {
                int lr = tid >> 3, g = tid & 7;
                int grow = m0 + (lr >> 4) * 64 + i * 16 + (lr & 15);
                unsigned short* dst = hbuf + (size_t)grow * HID + nt * 128;
                *reinterpret_cast<bf16x8*>(dst + g * 8) =
                    *reinterpret_cast<const bf16x8*>(&X[lr][g * 8]);
                *reinterpret_cast<bf16x8*>(dst + 64 + g * 8) =
                    *reinterpret_cast<const bf16x8*>(&X[lr][64 + g * 8]);
            }
            __syncthreads();
        }
    } else {
        // ---- coalesced out epilogue: padded f32 transpose ----
        // g2atomic==0: exclusive (token,col) ownership within the launch -> float4 RMW.
        // g2atomic==1: multiple G2 experts co-scheduled -> atomicAdd in FLAT order:
        //   wave lanes hit consecutive floats (256B/instr), not 64B-strided (r9 bug).
        float (*Xf)[132] = reinterpret_cast<float (*)[132]>(smem);  // 16.9 KB of 32 KB
        #pragma unroll
        for (int i = 0; i < 4; ++i) {
            #pragma unroll
            for (int j = 0; j < 4; ++j) {
                float bias = b2[e * DIM + nb0 + j * 16 + col];
                #pragma unroll
                for (int r = 0; r < 4; ++r) {
                    int lrow = wm * 64 + i * 16 + quad * 4 + r;
                    float g = ssg[lrow];
                    float v = acc[i][j][r] + bias;
                    Xf[wm * 16 + quad * 4 + r][wn * 64 + j * 16 + col] =
                        (g > 0.0f) ? g * expf(v) : 0.0f;
                }
            }
            __syncthreads();
            if (g2atomic) {
                #pragma unroll
                for (int k = 0; k < 16; ++k) {
                    int flat = tid + k * 256;          // 0..4095 over 32x128 chunk
                    int lr2 = flat >> 7, c2 = flat & 127;
                    int lrow2 = (lr2 >> 4) * 64 + i * 16 + (lr2 & 15);
                    if (m0 + lrow2 < cnt)
                        atomicAdd(out + (size_t)sst[lrow2] * DIM + nt * 128 + c2,
                                  Xf[lr2][c2]);
                }
            } else {
                int lr = tid >> 3, gq = tid & 7;
                int lrow = (lr >> 4) * 64 + i * 16 + (lr & 15);
                if (m0 + lrow < cnt) {   // guard: padded rows must not RMW (token-0 race)
                    float* dst = out + (size_t)sst[lrow] * DIM + nt * 128 + gq * 16;
                    const float* src = &Xf[lr][gq * 16];
                    #pragma unroll
                    for (int q = 0; q < 4; ++q) {
                        float4 o = *reinterpret_cast<float4*>(dst + q * 4);
                        float4 a = *reinterpret_cast<const float4*>(src + q * 4);
                        o.x += a.x; o.y += a.y; o.z += a.z; o.w += a.w;
                        *reinterpret_cast<float4*>(dst + q * 4) = o;
                    }
                }
            }
            __syncthreads();
        }
    }
}

// ---------------- final: out = log(acc), eps guard ----------------
__global__ void log_kernel(float* __restrict__ out, int n) {
    int i = blockIdx.x * 256 + threadIdx.x;
    if (i < n) {
        float v = out[i];
        out[i] = logf(v == 0.0f ? EPSF : v);
    }
}

// ================= fallback path (used only if ws too small) =================
__global__ void prep_w1_v2(const float* __restrict__ W1, unsigned short* __restrict__ W1s) {
    int g = blockIdx.x * 4 + (threadIdx.x >> 6);
    int lane = threadIdx.x & 63;
    int kf = g % 48;
    int rest = g / 48;
    int nt2 = rest % 96;
    int e = rest / 96;
    int n = nt2 * 32 + (lane & 31);
    int k0 = kf * 16 + (lane >> 5) * 8;
    const float* src = W1 + ((size_t)e * DIM + k0) * HID + n;
    bf16x8 v;
    #pragma unroll
    for (int j = 0; j < 8; ++j) v[j] = (short)f2bf(src[(size_t)j * HID]);
    *reinterpret_cast<bf16x8*>(W1s + ((size_t)g * 64 + lane) * 8) = v;
}

__global__ void prep_w2_v2(const float* __restrict__ W2, unsigned short* __restrict__ W2s) {
    int g = blockIdx.x * 4 + (threadIdx.x >> 6);
    int lane = threadIdx.x & 63;
    int kf = g % 192;
    int rest = g / 192;
    int nt2 = rest % 24;
    int e = rest / 24;
    int n = nt2 * 32 + (lane & 31);
    int k0 = kf * 16 + (lane >> 5) * 8;
    const float* src = W2 + ((size_t)e * HID + k0) * DIM + n;
    bf16x8 v;
    #pragma unroll
    for (int j = 0; j < 8; ++j) v[j] = (short)f2bf(src[(size_t)j * DIM]);
    *reinterpret_cast<bf16x8*>(W2s + ((size_t)g * 64 + lane) * 8) = v;
}

__global__ __launch_bounds__(512, 2) void expert_v2(
    const unsigned short* __restrict__ xb, const unsigned short* __restrict__ W1s,
    const unsigned short* __restrict__ W2s, const float* __restrict__ b1,
    const float* __restrict__ b2, const int* __restrict__ counts,
    const int* __restrict__ btok, const float* __restrict__ bgate,
    float* __restrict__ out) {
    __shared__ __align__(16) unsigned short xs[64][776];
    __shared__ __align__(16) unsigned short hs[2][64][136];
    __shared__ int   st[64];
    __shared__ float sg[64];

    const int e = blockIdx.y;
    const int cnt = counts[e * CSTR];
    const int m0 = blockIdx.x * 64;
    if (m0 >= cnt) return;

    const int tid = threadIdx.x;
    const int wv = tid >> 6, lane = tid & 63;
    const int l31 = lane & 31, lhi = lane >> 5;

    if (tid < 64) {
        int pos = m0 + tid;
        st[tid] = (pos < cnt) ? btok[e * T_TOK + pos] : 0;
        sg[tid] = (pos < cnt) ? bgate[e * T_TOK + pos] : 0.0f;
    }
    __syncthreads();
    {
        int r = tid >> 3, seg = tid & 7;
        const unsigned short* src = xb + (size_t)st[r] * DIM + seg * 96;
        unsigned short* dst = &xs[r][seg * 96];
        #pragma unroll
        for (int i = 0; i < 12; ++i)
            reinterpret_cast<bf16x8*>(dst)[i] = reinterpret_cast<const bf16x8*>(src)[i];
    }
    __syncthreads();

    const int mt2 = wv & 1, nt2l = wv >> 1;
    f32x16 acc[2][3];
    #pragma unroll
    for (int a_ = 0; a_ < 2; ++a_)
        #pragma unroll
        for (int b_ = 0; b_ < 3; ++b_)
            #pragma unroll
            for (int q = 0; q < 16; ++q) acc[a_][b_][q] = 0.0f;

    const unsigned short* arow = &xs[mt2 * 32 + l31][lhi * 8];
    for (int jc = 0; jc < 24; ++jc) {
        f32x16 c0, c1;
        #pragma unroll
        for (int q = 0; q < 16; ++q) { c0[q] = 0.0f; c1[q] = 0.0f; }
        const unsigned short* bpa =
            W1s + ((size_t)((e * 96 + jc * 4 + nt2l) * 48)) * 512 + lane * 8;
        #pragma unroll
        for (int kf = 0; kf < 48; kf += 2) {
            bf16x8 a0 = *reinterpret_cast<const bf16x8*>(arow + kf * 16);
            bf16x8 b0 = *reinterpret_cast<const bf16x8*>(bpa + (size_t)kf * 512);
            c0 = MFMA32(a0, b0, c0);
            bf16x8 a1 = *reinterpret_cast<const bf16x8*>(arow + kf * 16 + 16);
            bf16x8 b1 = *reinterpret_cast<const bf16x8*>(bpa + (size_t)kf * 512 + 512);
            c1 = MFMA32(a1, b1, c1);
        }
        #pragma unroll
        for (int q = 0; q < 16; ++q) c0[q] += c1[q];
        {
            int colc = nt2l * 32 + l31;
            float bias = b1[e * HID + jc * 128 + colc];
            #pragma unroll
            for (int reg = 0; reg < 16; ++reg) {
                int row = (reg & 3) + 8 * (reg >> 2) + 4 * lhi;
                float v = c0[reg] + bias;
                float gl = 0.5f * v * (1.0f + erff(v * 0.70710678118654752f));
                hs[jc & 1][mt2 * 32 + row][colc] = f2bf(gl);
            }
        }
        __syncthreads();
        const unsigned short* bpb =
            W2s + ((size_t)((e * 24 + wv * 3) * 192 + jc * 8)) * 512 + lane * 8;
        #pragma unroll
        for (int kf = 0; kf < 8; ++kf) {
            bf16x8 af0 = *reinterpret_cast<const bf16x8*>(&hs[jc & 1][l31][kf * 16 + lhi * 8]);
            bf16x8 af1 = *reinterpret_cast<const bf16x8*>(&hs[jc & 1][32 + l31][kf * 16 + lhi * 8]);
            #pragma unroll
            for (int i = 0; i < 3; ++i) {
                bf16x8 bv = *reinterpret_cast<const bf16x8*>(bpb + ((size_t)i * 192 + kf) * 512);
                acc[0][i] = MFMA32(af0, bv, acc[0][i]);
                acc[1][i] = MFMA32(af1, bv, acc[1][i]);
            }
        }
    }
    #pragma unroll
    for (int mt = 0; mt < 2; ++mt) {
        #pragma unroll
        for (int i = 0; i < 3; ++i) {
            int cg = (wv * 3 + i) * 32 + l31;
            float bias2 = b2[e * DIM + cg];
            #pragma unroll
            for (int reg = 0; reg < 16; ++reg) {
                int row = mt * 32 + (reg & 3) + 8 * (reg >> 2) + 4 * lhi;
                float g = sg[row];
                if (g > 0.0f) {
                    float v = acc[mt][i][reg] + bias2;
                    atomicAdd(out + (size_t)st[row] * DIM + cg, g * expf(v));
                }
            }
        }
    }
}

// =====================================================================

extern "C" void kernel_launch(void* const* d_in, const int* in_sizes, int n_in,
                              void* d_out, int out_size, void* d_ws, size_t ws_size,
                              hipStream_t stream) {
    const float* x  = (const float*)d_in[0];
    const float* wg = (const float*)d_in[1];
    const float* W1 = (const float*)d_in[2];
    const float* b1 = (const float*)d_in[3];
    const float* W2 = (const float*)d_in[4];
    const float* b2 = (const float*)d_in[5];
    float* out = (float*)d_out;

    // workspace layout
    char* ws = (char*)d_ws;
    int*            counts = (int*)ws;                                   // 5*128B padded
    int*            btok   = (int*)(ws + 1024);                          // 320 KB
    float*          bgate  = (float*)(ws + 1024 + 327680);               // 320 KB
    unsigned short* xb     = (unsigned short*)(ws + 1024 + 2 * 327680);  // 24 MB
    unsigned short* W1b    = xb + (size_t)T_TOK * DIM;                   // 22.5 MB
    unsigned short* W2b    = W1b + (size_t)NE * DIM * HID;               // 22.5 MB
    unsigned short* hall   = W2b + (size_t)NE * HID * DIM;               // k x 48.75 MB

    const size_t HBsh  = (size_t)HCAP * HID;  // h bucket size in shorts
    const size_t fixed = 1024 + 2 * 327680
        + (size_t)T_TOK * DIM * 2 + 2 * (size_t)NE * DIM * HID * 2;
    auto need = [&](int k) { return fixed + (size_t)k * HBsh * 2; };

    const int g1seg = MT * 24, g2seg = MT * 6;

    hipMemsetAsync(counts, 0, 1024, stream);
    hipMemsetAsync(out, 0, (size_t)out_size * sizeof(float), stream);

    gate_kernel<<<T_TOK / 64, 256, 0, stream>>>(x, wg, xb, counts, btok, bgate);

    if (ws_size >= need(2)) {
        prep_w1p<<<(NE * 24 * 12 * 128 * 8 + 255) / 256, 256, 0, stream>>>(W1, W1b);
        prep_w2p<<<(NE * 6 * 48 * 128 * 8 + 255) / 256, 256, 0, stream>>>(W2, W2b);

        auto launch_combo = [&](int g1s, int g1n, int g2s, int g2n, int nslots) {
            int nb = g1n * g1seg + g2n * g2seg;
            if (nb <= 0) return;
            int g2atomic = (g2n > 1) ? 1 : 0;   // multi-G2 launch -> atomics (top-2 overlap)
            combo_kernel<<<nb, 256, 0, stream>>>(xb, W1b, W2b, b1, b2, counts,
                                                 btok, bgate, hall, nslots, out,
                                                 g1s, g1n, g2s, g2n, g2atomic);
        };

        if (ws_size >= need(5)) {
            // 2-launch: all G1, then all G2 (atomic).
            launch_combo(0, 5, 0, 0, 5);
            launch_combo(0, 0, 0, 5, 5);
        } else if (ws_size >= need(4)) {
            // 4 buckets (slot = e%4; e4 reuses e0's dead slot).
            launch_combo(0, 2, 0, 0, 4);
            launch_combo(2, 2, 0, 1, 4);
            launch_combo(4, 1, 1, 2, 4);
            launch_combo(0, 0, 3, 2, 4);
        } else if (ws_size >= need(3)) {
            // 3 buckets (slot = e%3), 4-launch pipeline, h-slot conflict-free:
            //  L1: G1(0)->s0, G1(1)->s1
            //  L2: G1(2)->s2 | G2(0)<-s0, G2(1)<-s1   [atomic: experts share tokens]
            //  L3: G1(3)->s0, G1(4)->s1 | G2(2)<-s2   [non-atomic]
            //  L4: G2(3)<-s0, G2(4)<-s1               [atomic]
            launch_combo(0, 2, 0, 0, 3);
            launch_combo(2, 1, 0, 2, 3);
            launch_combo(3, 2, 2, 1, 3);
            launch_combo(0, 0, 3, 2, 3);
        } else {
            // 6-launch pipeline: G1(s) + G2(s-1), parity buckets (single-G2 -> RMW).
            for (int s = 0; s < 6; ++s)
                launch_combo(s, (s <= 4) ? 1 : 0, s - 1, (s >= 1) ? 1 : 0, 2);
        }
    } else {
        prep_w1_v2<<<NE * 96 * 48 / 4, 256, 0, stream>>>(W1, W1b);
        prep_w2_v2<<<NE * 24 * 192 / 4, 256, 0, stream>>>(W2, W2b);
        expert_v2<<<dim3(T_TOK / 64, NE), 512, 0, stream>>>(
            xb, W1b, W2b, b1, b2, counts, btok, bgate, out);
    }

    log_kernel<<<(out_size + 255) / 256, 256, 0, stream>>>(out, out_size);
}